// Round 3
// baseline (1604.812 us; speedup 1.0000x reference)
//
#include <hip/hip_runtime.h>
#include <math.h>

typedef _Float16 f16;
typedef _Float16 f16x8 __attribute__((ext_vector_type(8)));
typedef _Float16 f16x2 __attribute__((ext_vector_type(2)));
typedef float f32x4 __attribute__((ext_vector_type(4)));
typedef float f32x2 __attribute__((ext_vector_type(2)));

#define QMAXF 127.0f
#define EPSQ 1e-8f

__device__ __forceinline__ void gl_lds16(const f16* g, char* l) {
  __builtin_amdgcn_global_load_lds(
      (const __attribute__((address_space(1))) unsigned int*)g,
      (__attribute__((address_space(3))) unsigned int*)l, 16, 0, 0);
}

// Group-of-128 symmetric int8 fake-quant along last dim: fp32 in -> fp16 out.
// Exact reference math in fp32; only the final q*s -> fp16 cast loses precision.
__global__ __launch_bounds__(256)
void qdq_kernel(const float* __restrict__ in, f16* __restrict__ out, int n_groups) {
  int wid = blockIdx.x * 4 + (threadIdx.x >> 6);
  if (wid >= n_groups) return;
  int lane = threadIdx.x & 63;
  long base = (long)wid * 128 + lane * 2;
  f32x2 v = *(const f32x2*)(in + base);
  float m = fmaxf(fabsf(v.x), fabsf(v.y));
#pragma unroll
  for (int off = 32; off; off >>= 1) m = fmaxf(m, __shfl_xor(m, off));
  float s = fmaxf(m / QMAXF, EPSQ);
  float q0 = fminf(fmaxf(rintf(v.x / s), -QMAXF), QMAXF);
  float q1 = fminf(fmaxf(rintf(v.y / s), -QMAXF), QMAXF);
  f16x2 o;
  o.x = (f16)(q0 * s);
  o.y = (f16)(q1 * s);
  *(f16x2*)(out + base) = o;
}

// ---------------------------------------------------------------------------
// 256x256 tile, BK=64, 8 waves (2M x 4N), 512 thr, 128 KiB LDS double-buffer,
// 4 phases/K-tile with counted vmcnt (m201 schedule).
// NT layout: A [M][K], B [N][K] row-major. fp32 out.
// EPI=0: C = acc.   EPI=1: C[idx] = silu(Caux[idx]) * acc  (C may alias Caux).
//
// LDS layout (bytes): buf b at b*65536; regions A-lo 0, A-hi 16384,
// B-lo 32768, B-hi 49152. Each 16 KiB region = 16 subtiles of 1 KiB in MFMA
// FRAGMENT-LINEAR order: subtile s = i*2+kk (i = 16-row group, kk = k-half),
// lane slot l at s*1024 + l*16 holds row i*16+(l&15), k = kk*32+(l>>4)*8..+8.
// => every ds_read_b128 is 64 lanes x contiguous 1KB: ZERO bank conflicts.
// Staging keeps linear LDS dest (global_load_lds rule, m104); the fragment
// permutation is applied to the per-thread GLOBAL source address instead
// (m173 pattern; source-perm == read-perm, rule #21).
// Re-stage safety (unchanged from r2): A reads of tile t done by P1, B by P2;
// (t+2).A staged P2/P3 into cur, (t+1).B staged P0/P1 into nxt; vmcnt(4) at
// P3 drains everything except (t+2).A.
// ---------------------------------------------------------------------------
template<int EPI>
__global__ __launch_bounds__(512, 1)
void gemm256(const f16* __restrict__ A, const f16* __restrict__ B,
             float* C, const float* Caux, int M, int N, int K, int NBN) {
  extern __shared__ __align__(16) char smem[];
  const int tid = threadIdx.x;
  const int lane = tid & 63;
  const int wid = tid >> 6;
  const int wm = wid >> 2, wn = wid & 3;
  const int l15 = lane & 15, l16 = lane >> 4;

  // T1: XCD-aware block swizzle (grids are %8==0)
  const int nwg = gridDim.x;
  const int wg = ((int)blockIdx.x & 7) * (nwg >> 3) + ((int)blockIdx.x >> 3);
  const long m0 = (long)(wg / NBN) * 256;
  const long n0 = (long)(wg % NBN) * 256;

  // staging: thread stages phys bytes [ph,ph+16) of each 16KB region.
  // fragment-linear decode: s=ph>>10, l=(ph>>4)&63 ->
  //   row = (s>>1)*16 + (l&15), kelem = (s&1)*32 + (l>>4)*8
  const int ph0 = tid * 16;
  const int ph1 = ph0 + 8192;
  const int s0 = ph0 >> 10, sl0 = (ph0 >> 4) & 63;
  const int s1 = ph1 >> 10, sl1 = (ph1 >> 4) & 63;
  const long r0 = (long)(s0 >> 1) * 16 + (sl0 & 15);
  const long r1 = (long)(s1 >> 1) * 16 + (sl1 & 15);
  const int c0e = (s0 & 1) * 32 + (sl0 >> 4) * 8;
  const int c1e = (s1 & 1) * 32 + (sl1 >> 4) * 8;

  const f16* pAlo0 = A + (m0 + r0) * K + c0e;
  const f16* pAlo1 = A + (m0 + r1) * K + c1e;
  const f16* pAhi0 = A + (m0 + 128 + r0) * K + c0e;
  const f16* pAhi1 = A + (m0 + 128 + r1) * K + c1e;
  const f16* pBlo0 = B + (n0 + r0) * K + c0e;
  const f16* pBlo1 = B + (n0 + r1) * K + c1e;
  const f16* pBhi0 = B + (n0 + 128 + r0) * K + c0e;
  const f16* pBhi1 = B + (n0 + 128 + r1) * K + c1e;

  // fragment read bases: perfectly linear per subtile
  const int aR = wm * 16384 + lane * 16;                      // + (i*2+kk)*1024
  const int bR = 32768 + (wn >> 1) * 16384 + (wn & 1) * 8192 + lane * 16;  // + (j*2+kk)*1024

  f32x4 acc[8][4];
#pragma unroll
  for (int i = 0; i < 8; i++)
#pragma unroll
    for (int j = 0; j < 4; j++) acc[i][j] = (f32x4){0.f, 0.f, 0.f, 0.f};

  const int kT = K / 64;

  // prologue: t0 all 4 regions -> buf0; t1 A regions -> buf1; wait t0 (leave 4)
  gl_lds16(pAlo0, smem + 0 + ph0);      gl_lds16(pAlo1, smem + 0 + ph1);
  gl_lds16(pAhi0, smem + 16384 + ph0);  gl_lds16(pAhi1, smem + 16384 + ph1);
  gl_lds16(pBlo0, smem + 32768 + ph0);  gl_lds16(pBlo1, smem + 32768 + ph1);
  gl_lds16(pBhi0, smem + 49152 + ph0);  gl_lds16(pBhi1, smem + 49152 + ph1);
  {
    const long ka = (kT > 1) ? 64 : 0;
    gl_lds16(pAlo0 + ka, smem + 65536 + 0 + ph0);
    gl_lds16(pAlo1 + ka, smem + 65536 + 0 + ph1);
    gl_lds16(pAhi0 + ka, smem + 65536 + 16384 + ph0);
    gl_lds16(pAhi1 + ka, smem + 65536 + 16384 + ph1);
  }
  asm volatile("s_waitcnt vmcnt(4)" ::: "memory");
  __builtin_amdgcn_s_barrier();

  for (int t = 0; t < kT; ++t) {
    const int cur = (t & 1) << 16;
    const int nxt = cur ^ 65536;
    const long k1 = (long)((t + 1 < kT) ? t + 1 : kT - 1) * 64;
    const long k2 = (long)((t + 2 < kT) ? t + 2 : kT - 1) * 64;
    f16x8 af[8][2], bf[2][2];

    // ---- P0: ds_read A i0-3 (8) + B j0-1 (4); stage (t+1).Blo -> nxt
#pragma unroll
    for (int i = 0; i < 4; i++)
#pragma unroll
      for (int kk = 0; kk < 2; kk++)
        af[i][kk] = *(const f16x8*)(smem + cur + aR + (i * 2 + kk) * 1024);
#pragma unroll
    for (int jj = 0; jj < 2; jj++)
#pragma unroll
      for (int kk = 0; kk < 2; kk++)
        bf[jj][kk] = *(const f16x8*)(smem + cur + bR + (jj * 2 + kk) * 1024);
    gl_lds16(pBlo0 + k1, smem + nxt + 32768 + ph0);
    gl_lds16(pBlo1 + k1, smem + nxt + 32768 + ph1);
    __builtin_amdgcn_s_barrier();
    __builtin_amdgcn_s_setprio(1);
#pragma unroll
    for (int i = 0; i < 4; i++)
#pragma unroll
      for (int jj = 0; jj < 2; jj++)
#pragma unroll
        for (int kk = 0; kk < 2; kk++)
          acc[i][jj] = __builtin_amdgcn_mfma_f32_16x16x32_f16(af[i][kk], bf[jj][kk], acc[i][jj], 0, 0, 0);
    __builtin_amdgcn_s_setprio(0);
    __builtin_amdgcn_s_barrier();

    // ---- P1: ds_read A i4-7 (8); stage (t+1).Bhi -> nxt
#pragma unroll
    for (int i = 4; i < 8; i++)
#pragma unroll
      for (int kk = 0; kk < 2; kk++)
        af[i][kk] = *(const f16x8*)(smem + cur + aR + (i * 2 + kk) * 1024);
    gl_lds16(pBhi0 + k1, smem + nxt + 49152 + ph0);
    gl_lds16(pBhi1 + k1, smem + nxt + 49152 + ph1);
    __builtin_amdgcn_s_barrier();
    __builtin_amdgcn_s_setprio(1);
#pragma unroll
    for (int i = 4; i < 8; i++)
#pragma unroll
      for (int jj = 0; jj < 2; jj++)
#pragma unroll
        for (int kk = 0; kk < 2; kk++)
          acc[i][jj] = __builtin_amdgcn_mfma_f32_16x16x32_f16(af[i][kk], bf[jj][kk], acc[i][jj], 0, 0, 0);
    __builtin_amdgcn_s_setprio(0);
    __builtin_amdgcn_s_barrier();

    // ---- P2: ds_read B j2-3 (4); stage (t+2).Alo -> cur (A reads done @P1)
#pragma unroll
    for (int jj = 0; jj < 2; jj++)
#pragma unroll
      for (int kk = 0; kk < 2; kk++)
        bf[jj][kk] = *(const f16x8*)(smem + cur + bR + ((2 + jj) * 2 + kk) * 1024);
    gl_lds16(pAlo0 + k2, smem + cur + 0 + ph0);
    gl_lds16(pAlo1 + k2, smem + cur + 0 + ph1);
    __builtin_amdgcn_s_barrier();
    __builtin_amdgcn_s_setprio(1);
#pragma unroll
    for (int i = 0; i < 4; i++)
#pragma unroll
      for (int jj = 0; jj < 2; jj++)
#pragma unroll
        for (int kk = 0; kk < 2; kk++)
          acc[i][2 + jj] = __builtin_amdgcn_mfma_f32_16x16x32_f16(af[i][kk], bf[jj][kk], acc[i][2 + jj], 0, 0, 0);
    __builtin_amdgcn_s_setprio(0);
    __builtin_amdgcn_s_barrier();

    // ---- P3: stage (t+2).Ahi -> cur; MFMA i4-7 x j2-3; counted vmcnt
    gl_lds16(pAhi0 + k2, smem + cur + 16384 + ph0);
    gl_lds16(pAhi1 + k2, smem + cur + 16384 + ph1);
    __builtin_amdgcn_s_barrier();
    __builtin_amdgcn_s_setprio(1);
#pragma unroll
    for (int i = 4; i < 8; i++)
#pragma unroll
      for (int jj = 0; jj < 2; jj++)
#pragma unroll
        for (int kk = 0; kk < 2; kk++)
          acc[i][2 + jj] = __builtin_amdgcn_mfma_f32_16x16x32_f16(af[i][kk], bf[jj][kk], acc[i][2 + jj], 0, 0, 0);
    __builtin_amdgcn_s_setprio(0);
    // leave (t+2).Alo/Ahi (4 loads) in flight; everything older (incl. t+1) drained
    asm volatile("s_waitcnt vmcnt(4)" ::: "memory");
    __builtin_amdgcn_s_barrier();
  }

  // epilogue: C/D map col=lane&15, row=(lane>>4)*4+reg
#pragma unroll
  for (int i = 0; i < 8; i++)
#pragma unroll
    for (int j = 0; j < 4; j++)
#pragma unroll
      for (int r = 0; r < 4; r++) {
        long row = m0 + wm * 128 + i * 16 + l16 * 4 + r;
        long col = n0 + wn * 64 + j * 16 + l15;
        long idx = row * N + col;
        if (EPI == 0) {
          C[idx] = acc[i][j][r];
        } else {
          float g = Caux[idx];
          C[idx] = g / (1.f + expf(-g)) * acc[i][j][r];
        }
      }
}

extern "C" void kernel_launch(void* const* d_in, const int* in_sizes, int n_in,
                              void* d_out, int out_size, void* d_ws, size_t ws_size,
                              hipStream_t stream) {
  (void)n_in; (void)out_size;
  const float* x  = (const float*)d_in[0];
  const float* wg = (const float*)d_in[1];
  const float* wu = (const float*)d_in[2];
  const float* wd = (const float*)d_in[3];
  float* out = (float*)d_out;

  const long H = 4096;
  const long M = in_sizes[0] / H;   // 4096 (B*S)
  const long I = in_sizes[1] / H;   // 11008

  // workspace: xq | wgq | wuq | wdq | gate(fp32, becomes hidden in-place)
  // hq overlays the dead xq/wgq region after the up-GEMM.
  char* ws = (char*)d_ws;
  size_t off = 0;
  f16* xq  = (f16*)(ws + off); off += 2L * M * H;
  f16* wgq = (f16*)(ws + off); off += 2L * I * H;
  f16* wuq = (f16*)(ws + off); off += 2L * I * H;
  f16* wdq = (f16*)(ws + off); off += 2L * H * I;
  float* gate = (float*)(ws + off); off += 4L * M * I;
  f16* hq = (f16*)ws;  // overlay
  if (ws_size < off) return;

  auto kg0 = gemm256<0>;
  auto kg1 = gemm256<1>;
  hipFuncSetAttribute((const void*)kg0, hipFuncAttributeMaxDynamicSharedMemorySize, 131072);
  hipFuncSetAttribute((const void*)kg1, hipFuncAttributeMaxDynamicSharedMemorySize, 131072);

  // 1) fake-quant inputs/weights -> fp16
  {
    int g;
    g = (int)(M * H / 128);
    qdq_kernel<<<dim3((g + 3) / 4), dim3(256), 0, stream>>>(x, xq, g);
    g = (int)(I * H / 128);
    qdq_kernel<<<dim3((g + 3) / 4), dim3(256), 0, stream>>>(wg, wgq, g);
    qdq_kernel<<<dim3((g + 3) / 4), dim3(256), 0, stream>>>(wu, wuq, g);
    g = (int)(H * I / 128);
    qdq_kernel<<<dim3((g + 3) / 4), dim3(256), 0, stream>>>(wd, wdq, g);
  }

  const int NBN_I = (int)(I / 256);  // 43
  const int NBN_H = (int)(H / 256);  // 16
  const int grid_gu = (int)(M / 256) * NBN_I;  // 688 (%8==0)
  const int grid_dn = (int)(M / 256) * NBN_H;  // 256 (%8==0)

  // 2) gate = xq . wgq^T
  kg0<<<dim3(grid_gu), dim3(512), 131072, stream>>>(xq, wgq, gate, nullptr,
                                                    (int)M, (int)I, (int)H, NBN_I);
  // 3) hidden = silu(gate) * (xq . wuq^T), in-place over gate
  kg1<<<dim3(grid_gu), dim3(512), 131072, stream>>>(xq, wuq, gate, gate,
                                                    (int)M, (int)I, (int)H, NBN_I);
  // 4) fake-quant hidden -> fp16 hq (overlay)
  {
    int g = (int)(M * I / 128);
    qdq_kernel<<<dim3((g + 3) / 4), dim3(256), 0, stream>>>(gate, hq, g);
  }
  // 5) out = hq . wdq^T
  kg0<<<dim3(grid_dn), dim3(512), 131072, stream>>>(hq, wdq, out, nullptr,
                                                    (int)M, (int)H, (int)I, NBN_H);
}

// Round 4
// 1246.972 us; speedup vs baseline: 1.2870x; 1.2870x over previous
//
#include <hip/hip_runtime.h>
#include <math.h>

typedef int i32x4 __attribute__((ext_vector_type(4)));
typedef float f32x4 __attribute__((ext_vector_type(4)));
typedef float f32x2 __attribute__((ext_vector_type(2)));

#define QMAXF 127.0f
#define EPSQ 1e-8f

__device__ __forceinline__ void gl_lds16(const void* g, void* l) {
  __builtin_amdgcn_global_load_lds(
      (const __attribute__((address_space(1))) unsigned int*)g,
      (__attribute__((address_space(3))) unsigned int*)l, 16, 0, 0);
}
__device__ __forceinline__ void gl_lds4(const void* g, void* l) {
  __builtin_amdgcn_global_load_lds(
      (const __attribute__((address_space(1))) unsigned int*)g,
      (__attribute__((address_space(3))) unsigned int*)l, 4, 0, 0);
}

// Group-of-128 symmetric int8 quant: fp32 in -> int8 q + transposed scales.
// Exact reference math in fp32 (max/127, maximum(.,eps), divide, rint, clip).
// sT layout: [groups_per_row][R] so GEMMs read a group's scales contiguously.
__global__ __launch_bounds__(256)
void qdq8(const float* __restrict__ in, char* __restrict__ q,
          float* __restrict__ sT, long n_groups, int gpr, int R) {
  long wid = (long)blockIdx.x * 4 + (threadIdx.x >> 6);
  if (wid >= n_groups) return;
  int lane = threadIdx.x & 63;
  long base = wid * 128 + lane * 2;
  f32x2 v = *(const f32x2*)(in + base);
  float m = fmaxf(fabsf(v.x), fabsf(v.y));
#pragma unroll
  for (int off = 32; off; off >>= 1) m = fmaxf(m, __shfl_xor(m, off));
  float s = fmaxf(m / QMAXF, EPSQ);
  int q0 = (int)fminf(fmaxf(rintf(v.x / s), -QMAXF), QMAXF);
  int q1 = (int)fminf(fmaxf(rintf(v.y / s), -QMAXF), QMAXF);
  *(unsigned short*)(q + base) =
      (unsigned short)((q0 & 0xff) | ((q1 & 0xff) << 8));
  if (lane == 0) {
    long row = wid / gpr;
    long gc = wid - row * gpr;
    sT[gc * (long)R + row] = s;
  }
}

// ---------------------------------------------------------------------------
// int8 GEMM tile: 128x128 output, BK=128 (= one quant group), 4 waves (2x2),
// single-buffered LDS, __syncthreads pair per K-group (r1-proven skeleton).
// Per group: exact int32 MFMA accumulation (mfma_i32_16x16x64_i8 x2), then
// fp32 rescale acc += (s_a[row]*s_b[col]) * (float)iacc. NT layout, i8 = 1B.
// ---------------------------------------------------------------------------

// Fused gate/up GEMM + SwiGLU + hidden group-quant (group = this tile's 128
// cols). Writes hq int8 and s_h (transposed [G_I][M]).
__global__ __launch_bounds__(256, 2)
void gemm_gu_i8(const char* __restrict__ Aq, const char* __restrict__ Bg,
                const char* __restrict__ Bu,
                const float* __restrict__ sAT, const float* __restrict__ sGT,
                const float* __restrict__ sUT,
                char* __restrict__ Hq, float* __restrict__ sHT,
                int M, int N, int K, int NBN) {
  __shared__ char sA[16384];
  __shared__ char sBG[16384];
  __shared__ char sBU[16384];
  __shared__ float sSa[128], sSg[128], sSu[128];
  __shared__ float rmx[2][128];
  __shared__ float rs[128];

  const int tid = threadIdx.x;
  const int lane = tid & 63;
  const int wid = tid >> 6;
  const int wr = (wid >> 1) * 64;
  const int wc = (wid & 1) * 64;
  const int l15 = lane & 15, l16 = lane >> 4;

  const int nwg = gridDim.x;
  const int wg = ((int)blockIdx.x & 7) * (nwg >> 3) + ((int)blockIdx.x >> 3);
  const long m0 = (long)(wg / NBN) * 128;
  const long n0 = (long)(wg % NBN) * 128;

  // staging: 1024 x 16B chunks per 16KB tile; thread stages c = tid + 256k.
  // chunk c: row = c>>3, byte-off = (c&7)*16  (i8 row = 128 B, coalesced).
  const char* gA[4];
  const char* gG[4];
  const char* gU[4];
#pragma unroll
  for (int k = 0; k < 4; k++) {
    int c = tid + 256 * k;
    long row = c >> 3;
    int off = (c & 7) * 16;
    gA[k] = Aq + (m0 + row) * K + off;
    gG[k] = Bg + (n0 + row) * K + off;
    gU[k] = Bu + (n0 + row) * K + off;
  }

  f32x4 accg[4][4], accu[4][4];
#pragma unroll
  for (int i = 0; i < 4; i++)
#pragma unroll
    for (int j = 0; j < 4; j++) {
      accg[i][j] = (f32x4){0.f, 0.f, 0.f, 0.f};
      accu[i][j] = (f32x4){0.f, 0.f, 0.f, 0.f};
    }
  const i32x4 iz = {0, 0, 0, 0};

  const int KG = K >> 7;
  for (int g = 0; g < KG; ++g) {
    const long kb = (long)g << 7;
#pragma unroll
    for (int k = 0; k < 4; k++) {
      gl_lds16(gA[k] + kb, &sA[(tid + 256 * k) * 16]);
      gl_lds16(gG[k] + kb, &sBG[(tid + 256 * k) * 16]);
      gl_lds16(gU[k] + kb, &sBU[(tid + 256 * k) * 16]);
    }
    // group scales (contiguous, transposed layout). waves 0-1: sSa+sSu,
    // waves 2-3: sSg. lds base wave-uniform, global per-lane (m104 rule).
    if (wid < 2) {
      gl_lds4(sAT + (long)g * M + m0 + tid, &sSa[wid * 64]);
      gl_lds4(sUT + (long)g * N + n0 + tid, &sSu[wid * 64]);
    } else {
      gl_lds4(sGT + (long)g * N + n0 + (tid - 128), &sSg[(wid - 2) * 64]);
    }
    __syncthreads();

    i32x4 af[4][2];
#pragma unroll
    for (int i = 0; i < 4; i++)
#pragma unroll
      for (int kk = 0; kk < 2; kk++)
        af[i][kk] = *(const i32x4*)&sA[(wr + i * 16 + l15) * 128 + kk * 64 + l16 * 16];
    f32x4 sa4[4];
#pragma unroll
    for (int i = 0; i < 4; i++)
      sa4[i] = *(const f32x4*)&sSa[wr + i * 16 + l16 * 4];

#pragma unroll
    for (int j = 0; j < 4; j++) {
      i32x4 bgf[2], buf_[2];
#pragma unroll
      for (int kk = 0; kk < 2; kk++) {
        bgf[kk] = *(const i32x4*)&sBG[(wc + j * 16 + l15) * 128 + kk * 64 + l16 * 16];
        buf_[kk] = *(const i32x4*)&sBU[(wc + j * 16 + l15) * 128 + kk * 64 + l16 * 16];
      }
      float sbg = sSg[wc + j * 16 + l15];
      float sbu = sSu[wc + j * 16 + l15];
#pragma unroll
      for (int i = 0; i < 4; i++) {
        i32x4 tg = __builtin_amdgcn_mfma_i32_16x16x64_i8(af[i][0], bgf[0], iz, 0, 0, 0);
        tg = __builtin_amdgcn_mfma_i32_16x16x64_i8(af[i][1], bgf[1], tg, 0, 0, 0);
        i32x4 tu = __builtin_amdgcn_mfma_i32_16x16x64_i8(af[i][0], buf_[0], iz, 0, 0, 0);
        tu = __builtin_amdgcn_mfma_i32_16x16x64_i8(af[i][1], buf_[1], tu, 0, 0, 0);
#pragma unroll
        for (int r = 0; r < 4; r++) {
          accg[i][j][r] += (sa4[i][r] * sbg) * (float)tg[r];
          accu[i][j][r] += (sa4[i][r] * sbu) * (float)tu[r];
        }
      }
    }
    __syncthreads();
  }

  // ---- epilogue: h = silu(g)*u; per-row (128-col group) max -> s; quantize.
  // C/D map: col = l15, row(local) = wr + i*16 + l16*4 + r.
  float pm[4][4];
#pragma unroll
  for (int i = 0; i < 4; i++)
#pragma unroll
    for (int r = 0; r < 4; r++) pm[i][r] = 0.f;
#pragma unroll
  for (int i = 0; i < 4; i++)
#pragma unroll
    for (int j = 0; j < 4; j++)
#pragma unroll
      for (int r = 0; r < 4; r++) {
        float gv = accg[i][j][r];
        float h = gv / (1.f + expf(-gv)) * accu[i][j][r];
        accu[i][j][r] = h;
        pm[i][r] = fmaxf(pm[i][r], fabsf(h));
      }
  // reduce over the 16 l15-lanes (same row set)
#pragma unroll
  for (int i = 0; i < 4; i++)
#pragma unroll
    for (int r = 0; r < 4; r++) {
      pm[i][r] = fmaxf(pm[i][r], __shfl_xor(pm[i][r], 1));
      pm[i][r] = fmaxf(pm[i][r], __shfl_xor(pm[i][r], 2));
      pm[i][r] = fmaxf(pm[i][r], __shfl_xor(pm[i][r], 4));
      pm[i][r] = fmaxf(pm[i][r], __shfl_xor(pm[i][r], 8));
    }
#pragma unroll
  for (int i = 0; i < 4; i++)
#pragma unroll
    for (int r = 0; r < 4; r++)
      if (l15 == i * 4 + r) rmx[wid & 1][wr + i * 16 + l16 * 4 + r] = pm[i][r];
  __syncthreads();
  if (tid < 128) {
    float mx = fmaxf(rmx[0][tid], rmx[1][tid]);
    float s = fmaxf(mx / QMAXF, EPSQ);
    rs[tid] = s;
    sHT[(n0 >> 7) * (long)M + m0 + tid] = s;
  }
  __syncthreads();
  // quantize into sA (reused as transpose buffer), then coalesced copy out
#pragma unroll
  for (int i = 0; i < 4; i++) {
    f32x4 sr = *(const f32x4*)&rs[wr + i * 16 + l16 * 4];
#pragma unroll
    for (int j = 0; j < 4; j++)
#pragma unroll
      for (int r = 0; r < 4; r++) {
        float qv = fminf(fmaxf(rintf(accu[i][j][r] / sr[r]), -QMAXF), QMAXF);
        sA[(wr + i * 16 + l16 * 4 + r) * 128 + wc + j * 16 + l15] = (char)(int)qv;
      }
  }
  __syncthreads();
  {
    int row = tid >> 1, seg = tid & 1;
    const i32x4* src = (const i32x4*)&sA[row * 128 + seg * 64];
    i32x4* dst = (i32x4*)(Hq + (m0 + row) * N + n0 + seg * 64);
#pragma unroll
    for (int k = 0; k < 4; k++) dst[k] = src[k];
  }
}

// Down GEMM: fp32 out = dequant(A_i8) . dequant(B_i8)^T with exact int cores.
__global__ __launch_bounds__(256, 2)
void gemm_dn_i8(const char* __restrict__ Aq, const char* __restrict__ Bq,
                const float* __restrict__ sAT, const float* __restrict__ sBT,
                float* __restrict__ C, int M, int N, int K, int NBN) {
  __shared__ char sA[16384];
  __shared__ char sB[16384];
  __shared__ float sSa[128], sSb[128];

  const int tid = threadIdx.x;
  const int lane = tid & 63;
  const int wid = tid >> 6;
  const int wr = (wid >> 1) * 64;
  const int wc = (wid & 1) * 64;
  const int l15 = lane & 15, l16 = lane >> 4;

  const int nwg = gridDim.x;
  const int wg = ((int)blockIdx.x & 7) * (nwg >> 3) + ((int)blockIdx.x >> 3);
  const long m0 = (long)(wg / NBN) * 128;
  const long n0 = (long)(wg % NBN) * 128;

  const char* gA[4];
  const char* gB[4];
#pragma unroll
  for (int k = 0; k < 4; k++) {
    int c = tid + 256 * k;
    long row = c >> 3;
    int off = (c & 7) * 16;
    gA[k] = Aq + (m0 + row) * K + off;
    gB[k] = Bq + (n0 + row) * K + off;
  }

  f32x4 acc[4][4];
#pragma unroll
  for (int i = 0; i < 4; i++)
#pragma unroll
    for (int j = 0; j < 4; j++) acc[i][j] = (f32x4){0.f, 0.f, 0.f, 0.f};
  const i32x4 iz = {0, 0, 0, 0};

  const int KG = K >> 7;
  for (int g = 0; g < KG; ++g) {
    const long kb = (long)g << 7;
#pragma unroll
    for (int k = 0; k < 4; k++) {
      gl_lds16(gA[k] + kb, &sA[(tid + 256 * k) * 16]);
      gl_lds16(gB[k] + kb, &sB[(tid + 256 * k) * 16]);
    }
    if (wid < 2) {
      gl_lds4(sAT + (long)g * M + m0 + tid, &sSa[wid * 64]);
    } else {
      gl_lds4(sBT + (long)g * N + n0 + (tid - 128), &sSb[(wid - 2) * 64]);
    }
    __syncthreads();

    i32x4 af[4][2];
#pragma unroll
    for (int i = 0; i < 4; i++)
#pragma unroll
      for (int kk = 0; kk < 2; kk++)
        af[i][kk] = *(const i32x4*)&sA[(wr + i * 16 + l15) * 128 + kk * 64 + l16 * 16];
    f32x4 sa4[4];
#pragma unroll
    for (int i = 0; i < 4; i++)
      sa4[i] = *(const f32x4*)&sSa[wr + i * 16 + l16 * 4];

#pragma unroll
    for (int j = 0; j < 4; j++) {
      i32x4 bf[2];
#pragma unroll
      for (int kk = 0; kk < 2; kk++)
        bf[kk] = *(const i32x4*)&sB[(wc + j * 16 + l15) * 128 + kk * 64 + l16 * 16];
      float sb = sSb[wc + j * 16 + l15];
#pragma unroll
      for (int i = 0; i < 4; i++) {
        i32x4 t = __builtin_amdgcn_mfma_i32_16x16x64_i8(af[i][0], bf[0], iz, 0, 0, 0);
        t = __builtin_amdgcn_mfma_i32_16x16x64_i8(af[i][1], bf[1], t, 0, 0, 0);
#pragma unroll
        for (int r = 0; r < 4; r++)
          acc[i][j][r] += (sa4[i][r] * sb) * (float)t[r];
      }
    }
    __syncthreads();
  }

#pragma unroll
  for (int i = 0; i < 4; i++)
#pragma unroll
    for (int j = 0; j < 4; j++)
#pragma unroll
      for (int r = 0; r < 4; r++) {
        long row = m0 + wr + i * 16 + l16 * 4 + r;
        long col = n0 + wc + j * 16 + l15;
        C[row * N + col] = acc[i][j][r];
      }
}

extern "C" void kernel_launch(void* const* d_in, const int* in_sizes, int n_in,
                              void* d_out, int out_size, void* d_ws, size_t ws_size,
                              hipStream_t stream) {
  (void)n_in; (void)out_size;
  const float* x  = (const float*)d_in[0];
  const float* wg = (const float*)d_in[1];
  const float* wu = (const float*)d_in[2];
  const float* wd = (const float*)d_in[3];
  float* out = (float*)d_out;

  const long H = 4096;
  const long M = in_sizes[0] / H;   // 4096 (B*S)
  const long I = in_sizes[1] / H;   // 11008
  const long GH = H >> 7;           // 32
  const long GI = I >> 7;           // 86

  // workspace: int8 tensors + transposed scale arrays (~204 MB total)
  char* ws = (char*)d_ws;
  size_t off = 0;
  char* xq  = ws + off; off += (size_t)(M * H);
  char* wgq = ws + off; off += (size_t)(I * H);
  char* wuq = ws + off; off += (size_t)(I * H);
  char* wdq = ws + off; off += (size_t)(H * I);
  char* hq  = ws + off; off += (size_t)(M * I);
  float* s_x = (float*)(ws + off); off += (size_t)(GH * M) * 4;
  float* s_g = (float*)(ws + off); off += (size_t)(GH * I) * 4;
  float* s_u = (float*)(ws + off); off += (size_t)(GH * I) * 4;
  float* s_d = (float*)(ws + off); off += (size_t)(GI * H) * 4;
  float* s_h = (float*)(ws + off); off += (size_t)(GI * M) * 4;
  if (ws_size < off) return;

  // 1) int8 group-quant of inputs/weights (q + transposed scales)
  {
    long ng;
    ng = M * H / 128;
    qdq8<<<dim3((unsigned)((ng + 3) / 4)), dim3(256), 0, stream>>>(x, xq, s_x, ng, (int)GH, (int)M);
    ng = I * H / 128;
    qdq8<<<dim3((unsigned)((ng + 3) / 4)), dim3(256), 0, stream>>>(wg, wgq, s_g, ng, (int)GH, (int)I);
    qdq8<<<dim3((unsigned)((ng + 3) / 4)), dim3(256), 0, stream>>>(wu, wuq, s_u, ng, (int)GH, (int)I);
    ng = H * I / 128;
    qdq8<<<dim3((unsigned)((ng + 3) / 4)), dim3(256), 0, stream>>>(wd, wdq, s_d, ng, (int)GI, (int)H);
  }

  // 2) fused gate/up int8 GEMM + SwiGLU + hidden quant -> hq, s_h
  {
    const int NBN = (int)GI;                       // 86
    const int grid = (int)(M / 128) * NBN;         // 2752 (%8==0)
    gemm_gu_i8<<<dim3(grid), dim3(256), 0, stream>>>(
        xq, wgq, wuq, s_x, s_g, s_u, hq, s_h, (int)M, (int)I, (int)H, NBN);
  }
  // 3) down int8 GEMM -> fp32 out
  {
    const int NBN = (int)GH;                       // 32
    const int grid = (int)(M / 128) * NBN;         // 1024 (%8==0)
    gemm_dn_i8<<<dim3(grid), dim3(256), 0, stream>>>(
        hq, wdq, s_h, s_d, out, (int)M, (int)H, (int)I, NBN);
  }
}

// Round 5
// 1171.605 us; speedup vs baseline: 1.3698x; 1.0643x over previous
//
#include <hip/hip_runtime.h>
#include <math.h>

typedef int i32x4 __attribute__((ext_vector_type(4)));
typedef float f32x4 __attribute__((ext_vector_type(4)));
typedef float f32x2 __attribute__((ext_vector_type(2)));

#define QMAXF 127.0f
#define EPSQ 1e-8f

__device__ __forceinline__ void gl_lds16(const void* g, void* l) {
  __builtin_amdgcn_global_load_lds(
      (const __attribute__((address_space(1))) unsigned int*)g,
      (__attribute__((address_space(3))) unsigned int*)l, 16, 0, 0);
}
__device__ __forceinline__ void gl_lds4(const void* g, void* l) {
  __builtin_amdgcn_global_load_lds(
      (const __attribute__((address_space(1))) unsigned int*)g,
      (__attribute__((address_space(3))) unsigned int*)l, 4, 0, 0);
}

// Group-of-128 symmetric int8 quant: fp32 in -> int8 q + transposed scales.
// Exact reference math in fp32 (max/127, maximum(.,eps), divide, rint, clip).
// sT layout: [groups_per_row][R] so GEMMs read a group's scales contiguously.
__global__ __launch_bounds__(256)
void qdq8(const float* __restrict__ in, char* __restrict__ q,
          float* __restrict__ sT, long n_groups, int gpr, int R) {
  long wid = (long)blockIdx.x * 4 + (threadIdx.x >> 6);
  if (wid >= n_groups) return;
  int lane = threadIdx.x & 63;
  long base = wid * 128 + lane * 2;
  f32x2 v = *(const f32x2*)(in + base);
  float m = fmaxf(fabsf(v.x), fabsf(v.y));
#pragma unroll
  for (int off = 32; off; off >>= 1) m = fmaxf(m, __shfl_xor(m, off));
  float s = fmaxf(m / QMAXF, EPSQ);
  int q0 = (int)fminf(fmaxf(rintf(v.x / s), -QMAXF), QMAXF);
  int q1 = (int)fminf(fmaxf(rintf(v.y / s), -QMAXF), QMAXF);
  *(unsigned short*)(q + base) =
      (unsigned short)((q0 & 0xff) | ((q1 & 0xff) << 8));
  if (lane == 0) {
    long row = wid / gpr;
    long gc = wid - row * gpr;
    sT[gc * (long)R + row] = s;
  }
}

// ---------------------------------------------------------------------------
// int8 GEMM tile: 128x128 output, BK=128 (= one quant group), 4 waves (2x2),
// single-buffered LDS (r1 skeleton). Exact int32 MFMA per group, fp32 rescale.
//
// LDS tiles are [128 rows][128 B] with G4 XOR swizzle:
//   phys_col = logical_col ^ ((row & 7) << 4)
// Applied on BOTH sides (rule #21): staging computes the per-thread GLOBAL
// source with the same XOR (granule permutation stays within one 128 B row,
// so global coalescing is unchanged); fragment reads XOR their col field
// (row&7 == l15&7 -> each aligned 8-lane group covers all 8 granules ->
// conflict-free ds_read_b128).
// ---------------------------------------------------------------------------

// Fused gate/up GEMM + SwiGLU + hidden group-quant (group = this tile's 128
// cols). Writes hq int8 and s_h (transposed [G_I][M]).
__global__ __launch_bounds__(256, 2)
void gemm_gu_i8(const char* __restrict__ Aq, const char* __restrict__ Bg,
                const char* __restrict__ Bu,
                const float* __restrict__ sAT, const float* __restrict__ sGT,
                const float* __restrict__ sUT,
                char* __restrict__ Hq, float* __restrict__ sHT,
                int M, int N, int K, int NBN) {
  __shared__ char sA[16384];
  __shared__ char sBG[16384];
  __shared__ char sBU[16384];
  __shared__ float sSa[128], sSg[128], sSu[128];
  __shared__ float rmx[2][128];
  __shared__ float rs[128];

  const int tid = threadIdx.x;
  const int lane = tid & 63;
  const int wid = tid >> 6;
  const int wr = (wid >> 1) * 64;
  const int wc = (wid & 1) * 64;
  const int l15 = lane & 15, l16 = lane >> 4;

  const int nwg = gridDim.x;
  const int wg = ((int)blockIdx.x & 7) * (nwg >> 3) + ((int)blockIdx.x >> 3);
  const long m0 = (long)(wg / NBN) * 128;
  const long n0 = (long)(wg % NBN) * 128;

  // staging: 1024 x 16B chunks per 16KB tile; thread stages c = tid + 256k.
  // chunk c -> phys (row = c>>3, pcol = (c&7)*16); global col = pcol ^ swz(row).
  const char* gA[4];
  const char* gG[4];
  const char* gU[4];
#pragma unroll
  for (int k = 0; k < 4; k++) {
    int c = tid + 256 * k;
    long row = c >> 3;
    int off = ((c & 7) * 16) ^ ((int)(row & 7) << 4);
    gA[k] = Aq + (m0 + row) * K + off;
    gG[k] = Bg + (n0 + row) * K + off;
    gU[k] = Bu + (n0 + row) * K + off;
  }

  // fragment read col fields (logical kk*64 + l16*16, XOR'd by row swizzle)
  const int rdSwz = (l15 & 7) << 4;
  const int colK0 = (l16 * 16) ^ rdSwz;
  const int colK1 = (64 + l16 * 16) ^ rdSwz;

  f32x4 accg[4][4], accu[4][4];
#pragma unroll
  for (int i = 0; i < 4; i++)
#pragma unroll
    for (int j = 0; j < 4; j++) {
      accg[i][j] = (f32x4){0.f, 0.f, 0.f, 0.f};
      accu[i][j] = (f32x4){0.f, 0.f, 0.f, 0.f};
    }
  const i32x4 iz = {0, 0, 0, 0};

  const int KG = K >> 7;
  for (int g = 0; g < KG; ++g) {
    const long kb = (long)g << 7;
#pragma unroll
    for (int k = 0; k < 4; k++) {
      gl_lds16(gA[k] + kb, &sA[(tid + 256 * k) * 16]);
      gl_lds16(gG[k] + kb, &sBG[(tid + 256 * k) * 16]);
      gl_lds16(gU[k] + kb, &sBU[(tid + 256 * k) * 16]);
    }
    // group scales (contiguous, transposed layout). waves 0-1: sSa+sSu,
    // waves 2-3: sSg. lds base wave-uniform, global per-lane (m104 rule).
    if (wid < 2) {
      gl_lds4(sAT + (long)g * M + m0 + tid, &sSa[wid * 64]);
      gl_lds4(sUT + (long)g * N + n0 + tid, &sSu[wid * 64]);
    } else {
      gl_lds4(sGT + (long)g * N + n0 + (tid - 128), &sSg[(wid - 2) * 64]);
    }
    __syncthreads();

    i32x4 af[4][2];
#pragma unroll
    for (int i = 0; i < 4; i++) {
      const int rb = (wr + i * 16 + l15) * 128;
      af[i][0] = *(const i32x4*)&sA[rb + colK0];
      af[i][1] = *(const i32x4*)&sA[rb + colK1];
    }
    f32x4 sa4[4];
#pragma unroll
    for (int i = 0; i < 4; i++)
      sa4[i] = *(const f32x4*)&sSa[wr + i * 16 + l16 * 4];

#pragma unroll
    for (int j = 0; j < 4; j++) {
      const int rbB = (wc + j * 16 + l15) * 128;
      i32x4 bgf[2], buf_[2];
      bgf[0] = *(const i32x4*)&sBG[rbB + colK0];
      bgf[1] = *(const i32x4*)&sBG[rbB + colK1];
      buf_[0] = *(const i32x4*)&sBU[rbB + colK0];
      buf_[1] = *(const i32x4*)&sBU[rbB + colK1];
      float sbg = sSg[wc + j * 16 + l15];
      float sbu = sSu[wc + j * 16 + l15];
#pragma unroll
      for (int i = 0; i < 4; i++) {
        i32x4 tg = __builtin_amdgcn_mfma_i32_16x16x64_i8(af[i][0], bgf[0], iz, 0, 0, 0);
        tg = __builtin_amdgcn_mfma_i32_16x16x64_i8(af[i][1], bgf[1], tg, 0, 0, 0);
        i32x4 tu = __builtin_amdgcn_mfma_i32_16x16x64_i8(af[i][0], buf_[0], iz, 0, 0, 0);
        tu = __builtin_amdgcn_mfma_i32_16x16x64_i8(af[i][1], buf_[1], tu, 0, 0, 0);
        f32x4 mg = sa4[i] * sbg;
        f32x4 mu = sa4[i] * sbu;
        accg[i][j] += mg * __builtin_convertvector(tg, f32x4);
        accu[i][j] += mu * __builtin_convertvector(tu, f32x4);
      }
    }
    __syncthreads();
  }

  // ---- epilogue: h = silu(g)*u; per-row (128-col group) max -> s; quantize.
  // C/D map: col = l15, row(local) = wr + i*16 + l16*4 + r.
  float pm[4][4];
#pragma unroll
  for (int i = 0; i < 4; i++)
#pragma unroll
    for (int r = 0; r < 4; r++) pm[i][r] = 0.f;
#pragma unroll
  for (int i = 0; i < 4; i++)
#pragma unroll
    for (int j = 0; j < 4; j++)
#pragma unroll
      for (int r = 0; r < 4; r++) {
        float gv = accg[i][j][r];
        float h = gv / (1.f + expf(-gv)) * accu[i][j][r];
        accu[i][j][r] = h;
        pm[i][r] = fmaxf(pm[i][r], fabsf(h));
      }
  // reduce over the 16 l15-lanes (same row set)
#pragma unroll
  for (int i = 0; i < 4; i++)
#pragma unroll
    for (int r = 0; r < 4; r++) {
      pm[i][r] = fmaxf(pm[i][r], __shfl_xor(pm[i][r], 1));
      pm[i][r] = fmaxf(pm[i][r], __shfl_xor(pm[i][r], 2));
      pm[i][r] = fmaxf(pm[i][r], __shfl_xor(pm[i][r], 4));
      pm[i][r] = fmaxf(pm[i][r], __shfl_xor(pm[i][r], 8));
    }
#pragma unroll
  for (int i = 0; i < 4; i++)
#pragma unroll
    for (int r = 0; r < 4; r++)
      if (l15 == i * 4 + r) rmx[wid & 1][wr + i * 16 + l16 * 4 + r] = pm[i][r];
  __syncthreads();
  if (tid < 128) {
    float mx = fmaxf(rmx[0][tid], rmx[1][tid]);
    float s = fmaxf(mx / QMAXF, EPSQ);
    rs[tid] = s;
    sHT[(n0 >> 7) * (long)M + m0 + tid] = s;
  }
  __syncthreads();
  // quantize into sA (reused as transpose buffer), then coalesced copy out
#pragma unroll
  for (int i = 0; i < 4; i++) {
    f32x4 sr = *(const f32x4*)&rs[wr + i * 16 + l16 * 4];
#pragma unroll
    for (int j = 0; j < 4; j++)
#pragma unroll
      for (int r = 0; r < 4; r++) {
        float qv = fminf(fmaxf(rintf(accu[i][j][r] / sr[r]), -QMAXF), QMAXF);
        sA[(wr + i * 16 + l16 * 4 + r) * 128 + wc + j * 16 + l15] = (char)(int)qv;
      }
  }
  __syncthreads();
  {
    int row = tid >> 1, seg = tid & 1;
    const i32x4* src = (const i32x4*)&sA[row * 128 + seg * 64];
    i32x4* dst = (i32x4*)(Hq + (m0 + row) * N + n0 + seg * 64);
#pragma unroll
    for (int k = 0; k < 4; k++) dst[k] = src[k];
  }
}

// Down GEMM: fp32 out = dequant(A_i8) . dequant(B_i8)^T with exact int cores.
__global__ __launch_bounds__(256, 2)
void gemm_dn_i8(const char* __restrict__ Aq, const char* __restrict__ Bq,
                const float* __restrict__ sAT, const float* __restrict__ sBT,
                float* __restrict__ C, int M, int N, int K, int NBN) {
  __shared__ char sA[16384];
  __shared__ char sB[16384];
  __shared__ float sSa[128], sSb[128];

  const int tid = threadIdx.x;
  const int lane = tid & 63;
  const int wid = tid >> 6;
  const int wr = (wid >> 1) * 64;
  const int wc = (wid & 1) * 64;
  const int l15 = lane & 15, l16 = lane >> 4;

  const int nwg = gridDim.x;
  const int wg = ((int)blockIdx.x & 7) * (nwg >> 3) + ((int)blockIdx.x >> 3);
  const long m0 = (long)(wg / NBN) * 128;
  const long n0 = (long)(wg % NBN) * 128;

  const char* gA[4];
  const char* gB[4];
#pragma unroll
  for (int k = 0; k < 4; k++) {
    int c = tid + 256 * k;
    long row = c >> 3;
    int off = ((c & 7) * 16) ^ ((int)(row & 7) << 4);
    gA[k] = Aq + (m0 + row) * K + off;
    gB[k] = Bq + (n0 + row) * K + off;
  }

  const int rdSwz = (l15 & 7) << 4;
  const int colK0 = (l16 * 16) ^ rdSwz;
  const int colK1 = (64 + l16 * 16) ^ rdSwz;

  f32x4 acc[4][4];
#pragma unroll
  for (int i = 0; i < 4; i++)
#pragma unroll
    for (int j = 0; j < 4; j++) acc[i][j] = (f32x4){0.f, 0.f, 0.f, 0.f};
  const i32x4 iz = {0, 0, 0, 0};

  const int KG = K >> 7;
  for (int g = 0; g < KG; ++g) {
    const long kb = (long)g << 7;
#pragma unroll
    for (int k = 0; k < 4; k++) {
      gl_lds16(gA[k] + kb, &sA[(tid + 256 * k) * 16]);
      gl_lds16(gB[k] + kb, &sB[(tid + 256 * k) * 16]);
    }
    if (wid < 2) {
      gl_lds4(sAT + (long)g * M + m0 + tid, &sSa[wid * 64]);
    } else {
      gl_lds4(sBT + (long)g * N + n0 + (tid - 128), &sSb[(wid - 2) * 64]);
    }
    __syncthreads();

    i32x4 af[4][2];
#pragma unroll
    for (int i = 0; i < 4; i++) {
      const int rb = (wr + i * 16 + l15) * 128;
      af[i][0] = *(const i32x4*)&sA[rb + colK0];
      af[i][1] = *(const i32x4*)&sA[rb + colK1];
    }
    f32x4 sa4[4];
#pragma unroll
    for (int i = 0; i < 4; i++)
      sa4[i] = *(const f32x4*)&sSa[wr + i * 16 + l16 * 4];

#pragma unroll
    for (int j = 0; j < 4; j++) {
      const int rbB = (wc + j * 16 + l15) * 128;
      i32x4 bf[2];
      bf[0] = *(const i32x4*)&sB[rbB + colK0];
      bf[1] = *(const i32x4*)&sB[rbB + colK1];
      float sb = sSb[wc + j * 16 + l15];
#pragma unroll
      for (int i = 0; i < 4; i++) {
        i32x4 t = __builtin_amdgcn_mfma_i32_16x16x64_i8(af[i][0], bf[0], iz, 0, 0, 0);
        t = __builtin_amdgcn_mfma_i32_16x16x64_i8(af[i][1], bf[1], t, 0, 0, 0);
        f32x4 ms = sa4[i] * sb;
        acc[i][j] += ms * __builtin_convertvector(t, f32x4);
      }
    }
    __syncthreads();
  }

#pragma unroll
  for (int i = 0; i < 4; i++)
#pragma unroll
    for (int j = 0; j < 4; j++)
#pragma unroll
      for (int r = 0; r < 4; r++) {
        long row = m0 + wr + i * 16 + l16 * 4 + r;
        long col = n0 + wc + j * 16 + l15;
        C[row * N + col] = acc[i][j][r];
      }
}

extern "C" void kernel_launch(void* const* d_in, const int* in_sizes, int n_in,
                              void* d_out, int out_size, void* d_ws, size_t ws_size,
                              hipStream_t stream) {
  (void)n_in; (void)out_size;
  const float* x  = (const float*)d_in[0];
  const float* wg = (const float*)d_in[1];
  const float* wu = (const float*)d_in[2];
  const float* wd = (const float*)d_in[3];
  float* out = (float*)d_out;

  const long H = 4096;
  const long M = in_sizes[0] / H;   // 4096 (B*S)
  const long I = in_sizes[1] / H;   // 11008
  const long GH = H >> 7;           // 32
  const long GI = I >> 7;           // 86

  // workspace: int8 tensors + transposed scale arrays (~204 MB total)
  char* ws = (char*)d_ws;
  size_t off = 0;
  char* xq  = ws + off; off += (size_t)(M * H);
  char* wgq = ws + off; off += (size_t)(I * H);
  char* wuq = ws + off; off += (size_t)(I * H);
  char* wdq = ws + off; off += (size_t)(H * I);
  char* hq  = ws + off; off += (size_t)(M * I);
  float* s_x = (float*)(ws + off); off += (size_t)(GH * M) * 4;
  float* s_g = (float*)(ws + off); off += (size_t)(GH * I) * 4;
  float* s_u = (float*)(ws + off); off += (size_t)(GH * I) * 4;
  float* s_d = (float*)(ws + off); off += (size_t)(GI * H) * 4;
  float* s_h = (float*)(ws + off); off += (size_t)(GI * M) * 4;
  if (ws_size < off) return;

  // 1) int8 group-quant of inputs/weights (q + transposed scales)
  {
    long ng;
    ng = M * H / 128;
    qdq8<<<dim3((unsigned)((ng + 3) / 4)), dim3(256), 0, stream>>>(x, xq, s_x, ng, (int)GH, (int)M);
    ng = I * H / 128;
    qdq8<<<dim3((unsigned)((ng + 3) / 4)), dim3(256), 0, stream>>>(wg, wgq, s_g, ng, (int)GH, (int)I);
    qdq8<<<dim3((unsigned)((ng + 3) / 4)), dim3(256), 0, stream>>>(wu, wuq, s_u, ng, (int)GH, (int)I);
    ng = H * I / 128;
    qdq8<<<dim3((unsigned)((ng + 3) / 4)), dim3(256), 0, stream>>>(wd, wdq, s_d, ng, (int)GI, (int)H);
  }

  // 2) fused gate/up int8 GEMM + SwiGLU + hidden quant -> hq, s_h
  {
    const int NBN = (int)GI;                       // 86
    const int grid = (int)(M / 128) * NBN;         // 2752 (%8==0)
    gemm_gu_i8<<<dim3(grid), dim3(256), 0, stream>>>(
        xq, wgq, wuq, s_x, s_g, s_u, hq, s_h, (int)M, (int)I, (int)H, NBN);
  }
  // 3) down int8 GEMM -> fp32 out
  {
    const int NBN = (int)GH;                       // 32
    const int grid = (int)(M / 128) * NBN;         // 1024 (%8==0)
    gemm_dn_i8<<<dim3(grid), dim3(256), 0, stream>>>(
        hq, wdq, s_h, s_d, out, (int)M, (int)H, (int)I, NBN);
  }
}